// Round 1
// baseline (1160.014 us; speedup 1.0000x reference)
//
#include <hip/hip_runtime.h>

typedef unsigned short u16;
typedef __bf16 bf16x8 __attribute__((ext_vector_type(8)));
typedef float f32x4 __attribute__((ext_vector_type(4)));
typedef int   i32x4 __attribute__((ext_vector_type(4)));
typedef u16   u16x8 __attribute__((ext_vector_type(8)));
typedef u16   u16x4 __attribute__((ext_vector_type(4)));

// sizes: b=16, s=2048, d=512, depth=2
// ws layout (bytes):
//   0         : Abf   [32768][512] bf16  (32MB)  rmsnorm out / layer0 scan out
//   33554432  : nhb   [2048][16][512] bf16 (32MB) tanh(next_hidden), [t][b][col]
//   67108864  : ifb   [2048][16][512] bf16 (32MB) input_forget
//   100663296 : wib   [2][1024][512] bf16 (2MB)
//   102760448 : whq   [2][512][512] i8   (512KB)
//   103284736 : scp   [2] f32 absmax(Wh_l)
// total ~98.5MB

__device__ __forceinline__ u16 f2bf(float f) {
  unsigned u = __float_as_uint(f);
  return (u16)((u + 0x7FFFu + ((u >> 16) & 1u)) >> 16);
}
__device__ __forceinline__ float bf2f(u16 v) {
  return __uint_as_float(((unsigned)v) << 16);
}
__device__ __forceinline__ void g2lds16(const void* g, void* l) {
  __builtin_amdgcn_global_load_lds(
      (const __attribute__((address_space(1))) unsigned*)g,
      (__attribute__((address_space(3))) unsigned*)l, 16, 0, 0);
}

// ---------------- prep kernels ----------------

__global__ __launch_bounds__(256) void k_cvtwi(const float* __restrict__ wi,
                                               u16* __restrict__ wib) {
  const int i = blockIdx.x * 256 + threadIdx.x;  // over 2*1024*512/4 = 262144
  const float4 v = ((const float4*)wi)[i];
  u16x4 o = {f2bf(v.x), f2bf(v.y), f2bf(v.z), f2bf(v.w)};
  ((u16x4*)wib)[i] = o;
}

__global__ __launch_bounds__(1024) void k_absmax(const float* __restrict__ wh,
                                                 float* __restrict__ sc) {
  const float* p = wh + ((size_t)blockIdx.x << 18);  // 262144 per layer
  float m = 0.f;
  for (int i = threadIdx.x; i < 65536; i += 1024) {
    float4 v = ((const float4*)p)[i];
    m = fmaxf(m, fmaxf(fmaxf(fabsf(v.x), fabsf(v.y)),
                       fmaxf(fabsf(v.z), fabsf(v.w))));
  }
#pragma unroll
  for (int o = 32; o; o >>= 1) m = fmaxf(m, __shfl_xor(m, o));
  __shared__ float red[16];
  if ((threadIdx.x & 63) == 0) red[threadIdx.x >> 6] = m;
  __syncthreads();
  if (threadIdx.x == 0) {
    float mm = red[0];
#pragma unroll
    for (int i = 1; i < 16; ++i) mm = fmaxf(mm, red[i]);
    sc[blockIdx.x] = fmaxf(mm, 1e-20f);
  }
}

__device__ __forceinline__ signed char q8(float v) {
  return (signed char)(int)rintf(fminf(127.f, fmaxf(-127.f, v)));
}

__global__ __launch_bounds__(256) void k_quant(const float* __restrict__ wh,
                                               const float* __restrict__ sc,
                                               char* __restrict__ q) {
  const int layer = blockIdx.y;
  const int i = blockIdx.x * 256 + threadIdx.x;  // < 65536 (float4 units)
  const float s = 127.f / sc[layer];
  const float4 v = ((const float4*)(wh + ((size_t)layer << 18)))[i];
  char4 o;
  o.x = q8(v.x * s); o.y = q8(v.y * s); o.z = q8(v.z * s); o.w = q8(v.w * s);
  ((char4*)q)[(((size_t)layer) << 16) + i] = o;
}

// ---------------- rmsnorm ----------------

__global__ __launch_bounds__(256) void k_rms(const float* __restrict__ x,
                                             const float* __restrict__ gamma,
                                             u16* __restrict__ out) {
  const int row = (blockIdx.x << 2) + (threadIdx.x >> 6);  // wave per row
  const int lane = threadIdx.x & 63;
  const float4* xr = (const float4*)(x + ((size_t)row << 9));
  const float4 a = xr[lane * 2], b = xr[lane * 2 + 1];
  float ss = a.x * a.x + a.y * a.y + a.z * a.z + a.w * a.w +
             b.x * b.x + b.y * b.y + b.z * b.z + b.w * b.w;
#pragma unroll
  for (int o = 32; o; o >>= 1) ss += __shfl_xor(ss, o);
  const float scl = 22.627416997969522f / fmaxf(sqrtf(ss), 1e-12f); // sqrt(512)
  const float4* gr = (const float4*)gamma;
  const float4 g0 = gr[lane * 2], g1 = gr[lane * 2 + 1];
  u16x8 o;
  o[0] = f2bf(a.x * scl * (g0.x + 1.f));
  o[1] = f2bf(a.y * scl * (g0.y + 1.f));
  o[2] = f2bf(a.z * scl * (g0.z + 1.f));
  o[3] = f2bf(a.w * scl * (g0.w + 1.f));
  o[4] = f2bf(b.x * scl * (g1.x + 1.f));
  o[5] = f2bf(b.y * scl * (g1.y + 1.f));
  o[6] = f2bf(b.z * scl * (g1.z + 1.f));
  o[7] = f2bf(b.w * scl * (g1.w + 1.f));
  ((u16x8*)(out + ((size_t)row << 9)))[lane] = o;
}

// ---------------- GEMM: proj = A[32768,512] @ W[1024,512]^T ----------------
// 128x128 tile, BK=64, 4 waves (2x2), double-buffered global_load_lds,
// XOR-swizzled LDS (pre-swizzled source), epilogue: tanh for cols<512 -> nhb,
// raw -> ifb, layout [t][b][col].

__global__ __launch_bounds__(256) void k_gemm(const u16* __restrict__ A,
                                              const u16* __restrict__ W,
                                              u16* __restrict__ nhb,
                                              u16* __restrict__ ifb) {
  __shared__ __align__(16) char lds[2][32768];  // [buf][A 16KB | B 16KB]
  const int tid = threadIdx.x, lane = tid & 63;
  const int wid = tid >> 6, wm = wid >> 1, wn = wid & 1;
  const int m0 = blockIdx.x << 7, n0 = blockIdx.y << 7;
  const char* Ab = (const char*)A;
  const char* Wb = (const char*)W;
  const int r4 = tid >> 3, c8 = tid & 7;

  f32x4 acc[4][4] = {};

  auto stage = [&](int kt, int bi) {
    char* dst = lds[bi];
#pragma unroll
    for (int i = 0; i < 4; ++i) {
      const int row = r4 + (i << 5);
      const int sw = (c8 ^ (row & 7)) << 4;  // pre-swizzled source chunk
      g2lds16(Ab + (((size_t)(m0 + row)) << 10) + (kt << 7) + sw,
              dst + (row << 7) + (c8 << 4));
      g2lds16(Wb + (((size_t)(n0 + row)) << 10) + (kt << 7) + sw,
              dst + 16384 + (row << 7) + (c8 << 4));
    }
  };

  stage(0, 0);
  __syncthreads();
  int buf = 0;
  for (int kt = 0; kt < 8; ++kt) {
    if (kt < 7) stage(kt + 1, buf ^ 1);
    const char* as = lds[buf];
    const char* bs = lds[buf] + 16384;
#pragma unroll
    for (int ks = 0; ks < 2; ++ks) {
      bf16x8 af[4], bg[4];
#pragma unroll
      for (int f = 0; f < 4; ++f) {
        const int row = (wm << 6) + (f << 4) + (lane & 15);
        const int col = (wn << 6) + (f << 4) + (lane & 15);
        const int ch = (ks << 2) + (lane >> 4);
        af[f] = *(const bf16x8*)(as + (row << 7) + ((ch ^ (row & 7)) << 4));
        bg[f] = *(const bf16x8*)(bs + (col << 7) + ((ch ^ (col & 7)) << 4));
      }
#pragma unroll
      for (int fm = 0; fm < 4; ++fm)
#pragma unroll
        for (int fn = 0; fn < 4; ++fn)
          acc[fm][fn] = __builtin_amdgcn_mfma_f32_16x16x32_bf16(
              af[fm], bg[fn], acc[fm][fn], 0, 0, 0);
    }
    __syncthreads();
    buf ^= 1;
  }

  const bool isnh = (n0 < 512);  // uniform per block
#pragma unroll
  for (int fm = 0; fm < 4; ++fm)
#pragma unroll
    for (int fn = 0; fn < 4; ++fn)
#pragma unroll
      for (int r = 0; r < 4; ++r) {
        const int gm = m0 + (wm << 6) + (fm << 4) + ((lane >> 4) << 2) + r;
        const int gn = n0 + (wn << 6) + (fn << 4) + (lane & 15);
        const float v = acc[fm][fn][r];
        const int bbi = gm >> 11, t = gm & 2047;  // m = b*2048 + t
        const size_t idx = (((size_t)t << 4) + bbi) << 9;
        if (isnh) {
          const float e = __expf(2.f * v);  // tanh = 1 - 2/(e^{2v}+1)
          nhb[idx + gn] = f2bf(1.f - 2.f / (e + 1.f));
        } else {
          ifb[idx + (gn - 512)] = f2bf(v);
        }
      }
}

// ---------------- chunked scan with burn-in ----------------
// 64 chunks of L=32 steps, W=128 warmup steps (contraction burn-in).
// Block = 512 thr (8 waves). All 16 batches. C[batch, outcol] via
// mfma_i32_16x16x64_i8; Wh i8 resident in VGPRs (32 frags/lane);
// h f32 in registers (acc layout), h_q i8 in XOR-swizzled LDS (dbuf).

template <int LAST>
__global__ __launch_bounds__(512, 2) void k_scan(
    const u16* __restrict__ nhb, const u16* __restrict__ ifb,
    const signed char* __restrict__ whq, const float* __restrict__ scp,
    const float* __restrict__ bh, u16* __restrict__ outA,
    float* __restrict__ outF, const float* __restrict__ x) {

  __shared__ __align__(16) signed char hq[2][8192];  // [buf][16 b][512 k] i8
  const int tid = threadIdx.x, lane = tid & 63, w = tid >> 6;
  const int l15 = lane & 15, l4 = lane >> 4;
  const int t_real0 = blockIdx.x << 5;
  const int t0 = max(0, t_real0 - 128);
  const int tend = t_real0 + 32;
  const float dq = scp[0] * (1.f / 16129.f);  // aw/(127*127)

  // B-operand (Wh^T) fragments: wave owns outcols [w*64, w*64+64)
  i32x4 bw[4][8];
#pragma unroll
  for (int ct = 0; ct < 4; ++ct) {
    const signed char* wr =
        whq + (((size_t)((w << 6) + (ct << 4) + l15)) << 9) + (l4 << 4);
#pragma unroll
    for (int ks = 0; ks < 8; ++ks) bw[ct][ks] = *(const i32x4*)(wr + (ks << 6));
  }
  float bhv[4];
#pragma unroll
  for (int ct = 0; ct < 4; ++ct) bhv[ct] = bh[(w << 6) + (ct << 4) + l15];

  // zero h_q (both buffers)
  {
    const i32x4 z = {0, 0, 0, 0};
    ((i32x4*)hq)[tid] = z;
    ((i32x4*)hq)[tid + 512] = z;
  }
  float hst[4][4];
#pragma unroll
  for (int ct = 0; ct < 4; ++ct)
#pragma unroll
    for (int r = 0; r < 4; ++r) hst[ct][r] = 0.f;

  __syncthreads();

  int cur = 0;
  for (int t = t0; t < tend; ++t) {
    // issue this step's inputs early; latency hides under MFMA phase
    float nhc[4][4], ifc[4][4], xc[4][4];
    {
      const size_t tb = ((size_t)t) << 4;
#pragma unroll
      for (int ct = 0; ct < 4; ++ct) {
        const int col = (w << 6) + (ct << 4) + l15;
#pragma unroll
        for (int r = 0; r < 4; ++r) {
          const int bbi = (l4 << 2) + r;
          const size_t i1 = ((tb + bbi) << 9) + col;
          nhc[ct][r] = bf2f(nhb[i1]);
          ifc[ct][r] = bf2f(ifb[i1]);
          if (LAST && t >= t_real0)
            xc[ct][r] = x[((((size_t)bbi << 11) + t) << 9) + col];
        }
      }
    }

    // matvec: acc[b, outcol] = sum_k h_q[b,k] * whq[outcol,k]
    i32x4 acc[4] = {};
    const signed char* hcur = hq[cur];
#pragma unroll
    for (int ks = 0; ks < 8; ++ks) {
      const i32x4 a = *(const i32x4*)(
          hcur + (l15 << 9) + ((((ks << 2) + l4) ^ (l15 & 7)) << 4));
      acc[0] = __builtin_amdgcn_mfma_i32_16x16x64_i8(a, bw[0][ks], acc[0], 0, 0, 0);
      acc[1] = __builtin_amdgcn_mfma_i32_16x16x64_i8(a, bw[1][ks], acc[1], 0, 0, 0);
      acc[2] = __builtin_amdgcn_mfma_i32_16x16x64_i8(a, bw[2][ks], acc[2], 0, 0, 0);
      acc[3] = __builtin_amdgcn_mfma_i32_16x16x64_i8(a, bw[3][ks], acc[3], 0, 0, 0);
    }

    // gate + lerp + requantize + emit
    signed char* hn = hq[cur ^ 1];
    const bool emit = (t >= t_real0);
#pragma unroll
    for (int ct = 0; ct < 4; ++ct) {
      const int col = (w << 6) + (ct << 4) + l15;
#pragma unroll
      for (int r = 0; r < 4; ++r) {
        const int bbi = (l4 << 2) + r;
        const float z = (float)acc[ct][r] * dq + bhv[ct] + ifc[ct][r];
        const float fg = 1.f / (1.f + __expf(-z));
        float h = hst[ct][r];
        h += fg * (nhc[ct][r] - h);
        hst[ct][r] = h;
        const float qf = fminf(127.f, fmaxf(-127.f, h * 127.f));
        hn[(bbi << 9) + ((((col >> 4) ^ (bbi & 7)) << 4) | (col & 15))] =
            (signed char)(int)rintf(qf);
        if (emit) {
          const size_t oidx = ((((size_t)bbi << 11) + t) << 9) + col;
          if (LAST)
            outF[oidx] = h + xc[ct][r];
          else
            outA[oidx] = f2bf(h);
        }
      }
    }
    __syncthreads();
    cur ^= 1;
  }
}

// ---------------- launch ----------------

extern "C" void kernel_launch(void* const* d_in, const int* in_sizes, int n_in,
                              void* d_out, int out_size, void* d_ws,
                              size_t ws_size, hipStream_t stream) {
  const float* x = (const float*)d_in[0];
  const float* gamma = (const float*)d_in[1];
  const float* Wi = (const float*)d_in[2];
  const float* Wh = (const float*)d_in[3];
  const float* bh = (const float*)d_in[4];
  float* out = (float*)d_out;
  char* ws = (char*)d_ws;

  u16* Abf = (u16*)(ws);
  u16* nhb = (u16*)(ws + 33554432);
  u16* ifb = (u16*)(ws + 67108864);
  u16* wib = (u16*)(ws + 100663296);
  signed char* whq = (signed char*)(ws + 102760448);
  float* scp = (float*)(ws + 103284736);

  k_cvtwi<<<1024, 256, 0, stream>>>(Wi, wib);
  k_absmax<<<2, 1024, 0, stream>>>(Wh, scp);
  k_quant<<<dim3(256, 2), 256, 0, stream>>>(Wh, scp, (char*)whq);
  k_rms<<<8192, 256, 0, stream>>>(x, gamma, Abf);

  // layer 0
  k_gemm<<<dim3(256, 8), 256, 0, stream>>>(Abf, wib, nhb, ifb);
  k_scan<0><<<64, 512, 0, stream>>>(nhb, ifb, whq, scp, bh, Abf, nullptr,
                                    nullptr);
  // layer 1
  k_gemm<<<dim3(256, 8), 256, 0, stream>>>(Abf, wib + 524288, nhb, ifb);
  k_scan<1><<<64, 512, 0, stream>>>(nhb, ifb, whq + 262144, scp + 1, bh + 512,
                                    nullptr, out, x);
}